// Round 8
// baseline (94.766 us; speedup 1.0000x reference)
//
#include <hip/hip_runtime.h>
#include <hip/hip_bf16.h>
#include <hip/hip_fp8.h>

typedef __attribute__((ext_vector_type(4))) float f32x4;
typedef __attribute__((ext_vector_type(2))) unsigned long ulongx2;

#define DDIM 512
#define BK 64

// k-permutation within each 64-element k-block (one 16B chunk holds both
// kk-subfragments of one lane-group g):
//   r = k%64; g=(r&31)>>3; kk=r>>5; h=r&7; pos = g*16 + kk*8 + h
// So lane (group g) reads its full 16x16x32-pair operand as ONE dwordx4 at
// byte offset  row*512 + t*64 + g*16  — .x = kk=0 operand, .y = kk=1.

// ---------------- Kernel 1: normalize + pos-pair dot + fp8 permuted write ----
__global__ __launch_bounds__(256) void norm_pd_kernel(
    const float* __restrict__ ei, const float* __restrict__ ej,
    unsigned char* __restrict__ zq, float* __restrict__ pd,
    float* __restrict__ rowsum, int N) {
  const int k = blockIdx.x;
  const int t = threadIdx.x;
  const float2 a = *reinterpret_cast<const float2*>(ei + (size_t)k * DDIM + t * 2);
  const float2 b = *reinterpret_cast<const float2*>(ej + (size_t)k * DDIM + t * 2);
  float sii = a.x * a.x + a.y * a.y;
  float sjj = b.x * b.x + b.y * b.y;
  float sij = a.x * b.x + a.y * b.y;
#pragma unroll
  for (int off = 32; off; off >>= 1) {
    sii += __shfl_down(sii, off);
    sjj += __shfl_down(sjj, off);
    sij += __shfl_down(sij, off);
  }
  __shared__ float red[3][4];
  if ((t & 63) == 0) { red[0][t >> 6] = sii; red[1][t >> 6] = sjj; red[2][t >> 6] = sij; }
  __syncthreads();
  sii = red[0][0] + red[0][1] + red[0][2] + red[0][3];
  sjj = red[1][0] + red[1][1] + red[1][2] + red[1][3];
  sij = red[2][0] + red[2][1] + red[2][2] + red[2][3];
  const float rsi = rsqrtf(sii), rsj = rsqrtf(sjj);

  // permuted byte position for elements k0, k0+1 (same 8-run, adjacent)
  const int k0 = t * 2;
  const int kb = k0 >> 6, r = k0 & 63;
  const int g = (r & 31) >> 3, kk = r >> 5, h = r & 7;
  const int pos = (kb << 6) + g * 16 + kk * 8 + h;

  __hip_fp8_e4m3 qa0(a.x * rsi), qa1(a.y * rsi);
  __hip_fp8_e4m3 qb0(b.x * rsj), qb1(b.y * rsj);
  const unsigned short wa = (unsigned short)qa0.__x | ((unsigned short)qa1.__x << 8);
  const unsigned short wb = (unsigned short)qb0.__x | ((unsigned short)qb1.__x << 8);
  *reinterpret_cast<unsigned short*>(zq + (size_t)k * DDIM + pos) = wa;
  *reinterpret_cast<unsigned short*>(zq + (size_t)(N + k) * DDIM + pos) = wb;
  if (t == 0) { pd[k] = sij * rsi * rsj; rowsum[k] = 0.0f; rowsum[N + k] = 0.0f; }
}

// ---------------- Kernel 2: LDS-free barrier-free fp8 fused sim-GEMM -----------
// 128x128 tile, 4 waves, per-wave 64x64 output. Fragments loaded DIRECTLY from
// L2 (z = 4 MB, L2-resident) as one global_load_dwordx4 per frag; no LDS, no
// barriers — waves free-run, compiler pipelines loads/MFMAs with counted vmcnt.

#define MFMA8(A, B, C) __builtin_amdgcn_mfma_f32_16x16x32_fp8_fp8((long)(A), (long)(B), (C), 0, 0, 0)

__global__ __launch_bounds__(256) void simloss_main(
    const unsigned char* __restrict__ zq, float* __restrict__ rowsum, int nwg) {
  // ---- bijective XCD-chunk remap (nwg = 2080 = 8*260, r8 = 0) ----
  const int orig = blockIdx.x;
  const int q = nwg >> 3, r8 = nwg & 7;
  const int xcd = orig & 7, pos0 = orig >> 3;
  const int t0 = (xcd < r8 ? xcd * (q + 1) : r8 * (q + 1) + (xcd - r8) * q) + pos0;

  // ---- triangular decode: t0 -> (bx, by), bx <= by ----
  const float ff = sqrtf(8.0f * (float)t0 + 1.0f);
  int by = (int)((ff - 1.0f) * 0.5f);
  while ((by + 1) * (by + 2) / 2 <= t0) ++by;
  while (by * (by + 1) / 2 > t0) --by;
  const int bx = t0 - by * (by + 1) / 2;

  const int row0 = bx * 128;
  const int col0 = by * 128;

  const int tid = threadIdx.x;
  const int w = tid >> 6;    // wave 0..3
  const int l = tid & 63;
  const int wr = (w >> 1) * 64;  // wave row offset
  const int wc = (w & 1) * 64;   // wave col offset
  const int lrow = l & 15;
  const int g = l >> 4;          // lane k-group

  // per-lane fragment byte offsets (32-bit; +t*64 folds into the imm offset)
  int aoff[4], boff[4];
#pragma unroll
  for (int mf = 0; mf < 4; ++mf)
    aoff[mf] = (row0 + wr + mf * 16 + lrow) * DDIM + g * 16;
#pragma unroll
  for (int nf = 0; nf < 4; ++nf)
    boff[nf] = (col0 + wc + nf * 16 + lrow) * DDIM + g * 16;

  f32x4 acc[4][4] = {};

  // ---- K-loop: 8 tiles of BK=64, fully unrolled; no sync anywhere ----
#pragma unroll
  for (int t = 0; t < 8; ++t) {
    ulongx2 Af[4], Bf[4];
#pragma unroll
    for (int mf = 0; mf < 4; ++mf)
      Af[mf] = *reinterpret_cast<const ulongx2*>(zq + aoff[mf] + t * BK);
#pragma unroll
    for (int nf = 0; nf < 4; ++nf)
      Bf[nf] = *reinterpret_cast<const ulongx2*>(zq + boff[nf] + t * BK);
#pragma unroll
    for (int mf = 0; mf < 4; ++mf)
#pragma unroll
      for (int nf = 0; nf < 4; ++nf) {
        acc[mf][nf] = MFMA8(Af[mf].x, Bf[nf].x, acc[mf][nf]);
        acc[mf][nf] = MFMA8(Af[mf].y, Bf[nf].y, acc[mf][nf]);
      }
  }

  // ---- epilogue ----
  // frag (mf, nf): rows row0 + wr + mf*16 + lgrp*4 + rg, col col0 + wc + nf*16 + lcol
  const float C2L2E = 2.0f * 1.44269504088896340736f;  // 2 * log2(e)
  const int lgrp = l >> 4;
  const int lcol = l & 15;

#pragma unroll
  for (int mf = 0; mf < 4; ++mf)
#pragma unroll
    for (int nf = 0; nf < 4; ++nf)
#pragma unroll
      for (int rg = 0; rg < 4; ++rg)
        acc[mf][nf][rg] = exp2f(acc[mf][nf][rg] * C2L2E);

  // row sums over the tile's 128 cols (this wave's 64)
#pragma unroll
  for (int mf = 0; mf < 4; ++mf) {
    float rs[4];
#pragma unroll
    for (int rg = 0; rg < 4; ++rg) {
      float s = 0.0f;
#pragma unroll
      for (int nf = 0; nf < 4; ++nf) s += acc[mf][nf][rg];
      rs[rg] = s;
    }
#pragma unroll
    for (int off = 1; off < 16; off <<= 1) {
#pragma unroll
      for (int rg = 0; rg < 4; ++rg) rs[rg] += __shfl_xor(rs[rg], off);
    }
    if (lcol == 0) {
      const int rowb = row0 + wr + mf * 16 + lgrp * 4;
#pragma unroll
      for (int rg = 0; rg < 4; ++rg) atomicAdd(&rowsum[rowb + rg], rs[rg]);
    }
  }

  // column sums (mirror) — off-diagonal tiles only
  if (bx != by) {
#pragma unroll
    for (int nf = 0; nf < 4; ++nf) {
      float cs = 0.0f;
#pragma unroll
      for (int mf = 0; mf < 4; ++mf)
#pragma unroll
        for (int rg = 0; rg < 4; ++rg) cs += acc[mf][nf][rg];
      cs += __shfl_xor(cs, 16);
      cs += __shfl_xor(cs, 32);
      if (lgrp == 0) atomicAdd(&rowsum[col0 + wc + nf * 16 + lcol], cs);
    }
  }
}

// ---------------- Kernel 3: finalize (parallel, atomic partials) ----------------
__global__ __launch_bounds__(1024) void finalize_kernel(
    const float* __restrict__ rowsum, const float* __restrict__ pd,
    float* __restrict__ out, int M, int N) {
  const int i = blockIdx.x * 1024 + threadIdx.x;
  const float E2 = 7.38905609893065f;  // exp(2) — diagonal term (unit rows)
  float acc = 0.0f;
  if (i < M) {
    const float denom = rowsum[i] - E2;
    const int kk = (i < N) ? i : (i - N);
    acc = logf(denom) - 2.0f * pd[kk];
  }
#pragma unroll
  for (int off = 32; off; off >>= 1) acc += __shfl_down(acc, off);
  __shared__ float red[16];
  const int t = threadIdx.x;
  if ((t & 63) == 0) red[t >> 6] = acc;
  __syncthreads();
  if (t < 64) {
    float s = (t < 16) ? red[t] : 0.0f;
#pragma unroll
    for (int off = 8; off; off >>= 1) s += __shfl_down(s, off);
    if (t == 0) atomicAdd(out, s / (float)M);
  }
}

extern "C" void kernel_launch(void* const* d_in, const int* in_sizes, int n_in,
                              void* d_out, int out_size, void* d_ws, size_t ws_size,
                              hipStream_t stream) {
  const float* ei = (const float*)d_in[0];
  const float* ej = (const float*)d_in[1];
  float* out = (float*)d_out;

  const int N = in_sizes[0] / DDIM;  // 4096
  const int M = 2 * N;               // 8192
  const int NT = M / 128;            // 64 tiles per dim
  const int NTRI = NT * (NT + 1) / 2;  // 2080 blocks (= 8*260)

  char* ws = (char*)d_ws;
  unsigned char* zq = (unsigned char*)ws;                        // M * 512 fp8
  float* pd = (float*)(ws + (size_t)M * DDIM);                   // N f32
  float* rowsum = (float*)(ws + (size_t)M * DDIM + (size_t)N * 4);  // M f32

  hipMemsetAsync(out, 0, sizeof(float), stream);
  norm_pd_kernel<<<N, 256, 0, stream>>>(ei, ej, zq, pd, rowsum, N);
  simloss_main<<<NTRI, 256, 0, stream>>>(zq, rowsum, NTRI);
  finalize_kernel<<<(M + 1023) / 1024, 1024, 0, stream>>>(rowsum, pd, out, M, N);
}

// Round 9
// 50.888 us; speedup vs baseline: 1.8622x; 1.8622x over previous
//
#include <hip/hip_runtime.h>
#include <hip/hip_bf16.h>

typedef __attribute__((ext_vector_type(4))) int i32x4;

#define AS1 __attribute__((address_space(1)))
#define AS3 __attribute__((address_space(3)))

#define DDIM 512
#define BK 64

// ---------------- Kernel 1: normalize + pos-pair dot + int8 write ----------------
// zq[row][k] = round(127 * z_hat[row][k]), row-major, k-contiguous.
__global__ __launch_bounds__(256) void norm_pd_kernel(
    const float* __restrict__ ei, const float* __restrict__ ej,
    unsigned char* __restrict__ zq, float* __restrict__ pd,
    float* __restrict__ rowsum, int N) {
  const int k = blockIdx.x;
  const int t = threadIdx.x;
  const float2 a = *reinterpret_cast<const float2*>(ei + (size_t)k * DDIM + t * 2);
  const float2 b = *reinterpret_cast<const float2*>(ej + (size_t)k * DDIM + t * 2);
  float sii = a.x * a.x + a.y * a.y;
  float sjj = b.x * b.x + b.y * b.y;
  float sij = a.x * b.x + a.y * b.y;
#pragma unroll
  for (int off = 32; off; off >>= 1) {
    sii += __shfl_down(sii, off);
    sjj += __shfl_down(sjj, off);
    sij += __shfl_down(sij, off);
  }
  __shared__ float red[3][4];
  if ((t & 63) == 0) { red[0][t >> 6] = sii; red[1][t >> 6] = sjj; red[2][t >> 6] = sij; }
  __syncthreads();
  sii = red[0][0] + red[0][1] + red[0][2] + red[0][3];
  sjj = red[1][0] + red[1][1] + red[1][2] + red[1][3];
  sij = red[2][0] + red[2][1] + red[2][2] + red[2][3];
  const float rsi = rsqrtf(sii), rsj = rsqrtf(sjj);

  const int qa0 = (int)rintf(127.0f * a.x * rsi);
  const int qa1 = (int)rintf(127.0f * a.y * rsi);
  const int qb0 = (int)rintf(127.0f * b.x * rsj);
  const int qb1 = (int)rintf(127.0f * b.y * rsj);
  const unsigned short wa = (unsigned short)(qa0 & 0xff) | ((unsigned short)(qa1 & 0xff) << 8);
  const unsigned short wb = (unsigned short)(qb0 & 0xff) | ((unsigned short)(qb1 & 0xff) << 8);
  *reinterpret_cast<unsigned short*>(zq + (size_t)k * DDIM + t * 2) = wa;
  *reinterpret_cast<unsigned short*>(zq + (size_t)(N + k) * DDIM + t * 2) = wb;
  if (t == 0) { pd[k] = sij * rsi * rsj; rowsum[k] = 0.0f; rowsum[N + k] = 0.0f; }
}

// ---------------- Kernel 2: int8 MFMA fused sim-GEMM ---------------------------
// 128x128 tile, 4 waves (64x64/wave), BK=64 -> ONE mfma_i32_16x16x64_i8 per
// (mf,nf) per K-tile. Double-buffered LDS (32 KiB), R3-proven control flow:
// stage(t+1); vmcnt(4); barrier; compute(t); barrier. 4 blocks/CU co-resident
// hide the barrier drains (m114). LDS chunk swizzle s=(g+(row>>1))&3 applied
// at the pre-swizzled global source AND ds_read (rule #21) -> 2-way (free).

#define MFMAI8(A, B, C) __builtin_amdgcn_mfma_i32_16x16x64_i8((A), (B), (C), 0, 0, 0)

__global__ __launch_bounds__(256, 4) void simloss_main(
    const unsigned char* __restrict__ zq, float* __restrict__ rowsum, int nwg) {
  // ---- bijective XCD-chunk remap (nwg = 2080 = 8*260, r8 = 0) ----
  const int orig = blockIdx.x;
  const int q = nwg >> 3, r8 = nwg & 7;
  const int xcd = orig & 7, pos0 = orig >> 3;
  const int t0 = (xcd < r8 ? xcd * (q + 1) : r8 * (q + 1) + (xcd - r8) * q) + pos0;

  // ---- triangular decode: t0 -> (bx, by), bx <= by ----
  const float ff = sqrtf(8.0f * (float)t0 + 1.0f);
  int by = (int)((ff - 1.0f) * 0.5f);
  while ((by + 1) * (by + 2) / 2 <= t0) ++by;
  while (by * (by + 1) / 2 > t0) --by;
  const int bx = t0 - by * (by + 1) / 2;

  const int row0 = bx * 128;
  const int col0 = by * 128;

  __shared__ unsigned char lds[2][2][8192];  // [buf][A,B][128 rows x 64 B]

  const int tid = threadIdx.x;
  const int w = tid >> 6;        // wave 0..3
  const int l = tid & 63;
  const int wr = (w >> 1) * 64;  // wave row offset in tile
  const int wc = (w & 1) * 64;   // wave col offset in tile
  const int lrow = l & 15;
  const int g = l >> 4;          // lane chunk-group (16B of k)

  i32x4 acc[4][4] = {};

  // stage one 128x64B half (A or B panel k-slab) into lds[buf][half]
  auto stage_half = [&](int buf, int half, int baserow, int k0) {
#pragma unroll
    for (int it = 0; it < 2; ++it) {
      const int p = it * 256 + tid;      // 16B chunk id 0..511
      const int row = p >> 2;            // 0..127
      const int s = p & 3;               // stored chunk slot
      const int gs = (s - (row >> 1)) & 3;  // source chunk (swizzle inverse)
      const unsigned char* src = zq + (size_t)(baserow + row) * DDIM + k0 + gs * 16;
      char* dst = (char*)&lds[buf][half][0] + (unsigned)((it * 256 + w * 64) * 16);
      __builtin_amdgcn_global_load_lds((const AS1 void*)src, (AS3 void*)dst, 16, 0, 0);
    }
  };

  auto compute = [&](int buf) {
    const unsigned char* ab = &lds[buf][0][0];
    const unsigned char* bb = &lds[buf][1][0];
    i32x4 Af[4], Bf[4];
#pragma unroll
    for (int mf = 0; mf < 4; ++mf) {
      const int r = wr + mf * 16 + lrow;
      Af[mf] = *reinterpret_cast<const i32x4*>(ab + r * 64 + (((g + (r >> 1)) & 3) << 4));
    }
#pragma unroll
    for (int nf = 0; nf < 4; ++nf) {
      const int c = wc + nf * 16 + lrow;
      Bf[nf] = *reinterpret_cast<const i32x4*>(bb + c * 64 + (((g + (c >> 1)) & 3) << 4));
    }
#pragma unroll
    for (int mf = 0; mf < 4; ++mf)
#pragma unroll
      for (int nf = 0; nf < 4; ++nf)
        acc[mf][nf] = MFMAI8(Af[mf], Bf[nf], acc[mf][nf]);
  };

  // ---- prologue ----
  stage_half(0, 0, row0, 0);
  stage_half(0, 1, col0, 0);

  // ---- K-loop: 8 tiles of BK=64 ----
  int buf = 0;
  for (int t = 0; t < 7; ++t) {
    stage_half(buf ^ 1, 0, row0, (t + 1) * BK);
    stage_half(buf ^ 1, 1, col0, (t + 1) * BK);
    asm volatile("s_waitcnt vmcnt(4)" ::: "memory");  // tile t's 4 loads landed
    __builtin_amdgcn_s_barrier();
    __builtin_amdgcn_sched_barrier(0);
    compute(buf);
    __builtin_amdgcn_sched_barrier(0);
    __builtin_amdgcn_s_barrier();
    buf ^= 1;
  }
  asm volatile("s_waitcnt vmcnt(0)" ::: "memory");
  __builtin_amdgcn_s_barrier();
  compute(buf);

  // ---- epilogue ----
  // C/D layout (16x16): col = l&15, row = (l>>4)*4 + reg
  const float SC = 2.0f * 1.44269504088896340736f / 16129.0f;  // 2*log2(e)/127^2
  const int lgrp = l >> 4;
  const int lcol = l & 15;

  float e[4][4][4];
#pragma unroll
  for (int mf = 0; mf < 4; ++mf)
#pragma unroll
    for (int nf = 0; nf < 4; ++nf)
#pragma unroll
      for (int rg = 0; rg < 4; ++rg)
        e[mf][nf][rg] = exp2f((float)acc[mf][nf][rg] * SC);

  // row sums (this wave's 64 cols)
#pragma unroll
  for (int mf = 0; mf < 4; ++mf) {
    float rs[4];
#pragma unroll
    for (int rg = 0; rg < 4; ++rg) {
      float s = 0.0f;
#pragma unroll
      for (int nf = 0; nf < 4; ++nf) s += e[mf][nf][rg];
      rs[rg] = s;
    }
#pragma unroll
    for (int off = 1; off < 16; off <<= 1) {
#pragma unroll
      for (int rg = 0; rg < 4; ++rg) rs[rg] += __shfl_xor(rs[rg], off);
    }
    if (lcol == 0) {
      const int rowb = row0 + wr + mf * 16 + lgrp * 4;
#pragma unroll
      for (int rg = 0; rg < 4; ++rg) atomicAdd(&rowsum[rowb + rg], rs[rg]);
    }
  }

  // column sums (mirror) — off-diagonal tiles only
  if (bx != by) {
#pragma unroll
    for (int nf = 0; nf < 4; ++nf) {
      float cs = 0.0f;
#pragma unroll
      for (int mf = 0; mf < 4; ++mf)
#pragma unroll
        for (int rg = 0; rg < 4; ++rg) cs += e[mf][nf][rg];
      cs += __shfl_xor(cs, 16);
      cs += __shfl_xor(cs, 32);
      if (lgrp == 0) atomicAdd(&rowsum[col0 + wc + nf * 16 + lcol], cs);
    }
  }
}

// ---------------- Kernel 3: finalize (parallel, atomic partials) ----------------
__global__ __launch_bounds__(1024) void finalize_kernel(
    const float* __restrict__ rowsum, const float* __restrict__ pd,
    float* __restrict__ out, int M, int N) {
  const int i = blockIdx.x * 1024 + threadIdx.x;
  const float E2 = 7.38905609893065f;  // exp(2) — diagonal term (unit rows)
  float acc = 0.0f;
  if (i < M) {
    const float denom = rowsum[i] - E2;
    const int kk = (i < N) ? i : (i - N);
    acc = logf(denom) - 2.0f * pd[kk];
  }
#pragma unroll
  for (int off = 32; off; off >>= 1) acc += __shfl_down(acc, off);
  __shared__ float red[16];
  const int t = threadIdx.x;
  if ((t & 63) == 0) red[t >> 6] = acc;
  __syncthreads();
  if (t < 64) {
    float s = (t < 16) ? red[t] : 0.0f;
#pragma unroll
    for (int off = 8; off; off >>= 1) s += __shfl_down(s, off);
    if (t == 0) atomicAdd(out, s / (float)M);
  }
}

extern "C" void kernel_launch(void* const* d_in, const int* in_sizes, int n_in,
                              void* d_out, int out_size, void* d_ws, size_t ws_size,
                              hipStream_t stream) {
  const float* ei = (const float*)d_in[0];
  const float* ej = (const float*)d_in[1];
  float* out = (float*)d_out;

  const int N = in_sizes[0] / DDIM;  // 4096
  const int M = 2 * N;               // 8192
  const int NT = M / 128;            // 64 tiles per dim
  const int NTRI = NT * (NT + 1) / 2;  // 2080 blocks (= 8*260)

  char* ws = (char*)d_ws;
  unsigned char* zq = (unsigned char*)ws;                        // M * 512 i8
  float* pd = (float*)(ws + (size_t)M * DDIM);                   // N f32
  float* rowsum = (float*)(ws + (size_t)M * DDIM + (size_t)N * 4);  // M f32

  hipMemsetAsync(out, 0, sizeof(float), stream);
  norm_pd_kernel<<<N, 256, 0, stream>>>(ei, ej, zq, pd, rowsum, N);
  simloss_main<<<NTRI, 256, 0, stream>>>(zq, rowsum, NTRI);
  finalize_kernel<<<(M + 1023) / 1024, 1024, 0, stream>>>(rowsum, pd, out, M, N);
}

// Round 10
// 46.046 us; speedup vs baseline: 2.0581x; 1.1052x over previous
//
#include <hip/hip_runtime.h>
#include <hip/hip_bf16.h>

typedef __attribute__((ext_vector_type(4))) int i32x4;

#define AS1 __attribute__((address_space(1)))
#define AS3 __attribute__((address_space(3)))

#define DDIM 512
#define BK 64

// ---------------- Kernel 1: normalize + pos-pair dot + int8 write ----------------
// zq[row][k] = round(127 * z_hat[row][k]), row-major, k-contiguous.
__global__ __launch_bounds__(256) void norm_pd_kernel(
    const float* __restrict__ ei, const float* __restrict__ ej,
    unsigned char* __restrict__ zq, float* __restrict__ pd,
    float* __restrict__ rowsum, float* __restrict__ out, int N) {
  const int k = blockIdx.x;
  const int t = threadIdx.x;
  const float2 a = *reinterpret_cast<const float2*>(ei + (size_t)k * DDIM + t * 2);
  const float2 b = *reinterpret_cast<const float2*>(ej + (size_t)k * DDIM + t * 2);
  float sii = a.x * a.x + a.y * a.y;
  float sjj = b.x * b.x + b.y * b.y;
  float sij = a.x * b.x + a.y * b.y;
#pragma unroll
  for (int off = 32; off; off >>= 1) {
    sii += __shfl_down(sii, off);
    sjj += __shfl_down(sjj, off);
    sij += __shfl_down(sij, off);
  }
  __shared__ float red[3][4];
  if ((t & 63) == 0) { red[0][t >> 6] = sii; red[1][t >> 6] = sjj; red[2][t >> 6] = sij; }
  __syncthreads();
  sii = red[0][0] + red[0][1] + red[0][2] + red[0][3];
  sjj = red[1][0] + red[1][1] + red[1][2] + red[1][3];
  sij = red[2][0] + red[2][1] + red[2][2] + red[2][3];
  const float rsi = rsqrtf(sii), rsj = rsqrtf(sjj);

  const int qa0 = (int)rintf(127.0f * a.x * rsi);
  const int qa1 = (int)rintf(127.0f * a.y * rsi);
  const int qb0 = (int)rintf(127.0f * b.x * rsj);
  const int qb1 = (int)rintf(127.0f * b.y * rsj);
  const unsigned short wa = (unsigned short)(qa0 & 0xff) | ((unsigned short)(qa1 & 0xff) << 8);
  const unsigned short wb = (unsigned short)(qb0 & 0xff) | ((unsigned short)(qb1 & 0xff) << 8);
  *reinterpret_cast<unsigned short*>(zq + (size_t)k * DDIM + t * 2) = wa;
  *reinterpret_cast<unsigned short*>(zq + (size_t)(N + k) * DDIM + t * 2) = wb;
  if (t == 0) {
    pd[k] = sij * rsi * rsj;
    rowsum[k] = 0.0f;
    rowsum[N + k] = 0.0f;
    if (k == 0) out[0] = 0.0f;
  }
}

// ---------------- Kernel 2: int8 MFMA fused sim-GEMM ---------------------------
// 128x128 tile, 4 waves (64x64/wave), BK=64 -> ONE mfma_i32_16x16x64_i8 per
// (mf,nf) per K-tile. Double-buffered LDS (32 KiB), fully-unrolled K-loop,
// counted vmcnt(4) + raw barriers, NO sched_barrier/setprio — the compiler
// software-pipelines; 5 blocks/CU co-resident hide the drains (m114/m97).
// LDS chunk swizzle s=(g+(row>>1))&3 applied at the pre-swizzled global
// source AND ds_read (rule #21) -> 2-way (free).

#define MFMAI8(A, B, C) __builtin_amdgcn_mfma_i32_16x16x64_i8((A), (B), (C), 0, 0, 0)

__global__ __launch_bounds__(256, 4) void simloss_main(
    const unsigned char* __restrict__ zq, float* __restrict__ rowsum, int nwg) {
  // ---- bijective XCD-chunk remap (nwg = 2080 = 8*260, r8 = 0) ----
  const int orig = blockIdx.x;
  const int q = nwg >> 3, r8 = nwg & 7;
  const int xcd = orig & 7, pos0 = orig >> 3;
  const int t0 = (xcd < r8 ? xcd * (q + 1) : r8 * (q + 1) + (xcd - r8) * q) + pos0;

  // ---- triangular decode: t0 -> (bx, by), bx <= by ----
  const float ff = sqrtf(8.0f * (float)t0 + 1.0f);
  int by = (int)((ff - 1.0f) * 0.5f);
  while ((by + 1) * (by + 2) / 2 <= t0) ++by;
  while (by * (by + 1) / 2 > t0) --by;
  const int bx = t0 - by * (by + 1) / 2;

  const int row0 = bx * 128;
  const int col0 = by * 128;

  __shared__ unsigned char lds[2][2][8192];  // [buf][A,B][128 rows x 64 B]

  const int tid = threadIdx.x;
  const int w = tid >> 6;        // wave 0..3
  const int l = tid & 63;
  const int wr = (w >> 1) * 64;  // wave row offset in tile
  const int wc = (w & 1) * 64;   // wave col offset in tile
  const int lrow = l & 15;
  const int g = l >> 4;          // lane chunk-group (16B of k)

  i32x4 acc[4][4] = {};

  // stage one 128x64B half (A or B panel k-slab) into lds[buf][half]
  auto stage_half = [&](int buf, int half, int baserow, int k0) {
#pragma unroll
    for (int it = 0; it < 2; ++it) {
      const int p = it * 256 + tid;      // 16B chunk id 0..511
      const int row = p >> 2;            // 0..127
      const int s = p & 3;               // stored chunk slot
      const int gs = (s - (row >> 1)) & 3;  // source chunk (swizzle inverse)
      const unsigned char* src = zq + (size_t)(baserow + row) * DDIM + k0 + gs * 16;
      char* dst = (char*)&lds[buf][half][0] + (unsigned)((it * 256 + w * 64) * 16);
      __builtin_amdgcn_global_load_lds((const AS1 void*)src, (AS3 void*)dst, 16, 0, 0);
    }
  };

  auto compute = [&](int buf) {
    const unsigned char* ab = &lds[buf][0][0];
    const unsigned char* bb = &lds[buf][1][0];
    i32x4 Af[4], Bf[4];
#pragma unroll
    for (int mf = 0; mf < 4; ++mf) {
      const int r = wr + mf * 16 + lrow;
      Af[mf] = *reinterpret_cast<const i32x4*>(ab + r * 64 + (((g + (r >> 1)) & 3) << 4));
    }
#pragma unroll
    for (int nf = 0; nf < 4; ++nf) {
      const int c = wc + nf * 16 + lrow;
      Bf[nf] = *reinterpret_cast<const i32x4*>(bb + c * 64 + (((g + (c >> 1)) & 3) << 4));
    }
#pragma unroll
    for (int mf = 0; mf < 4; ++mf)
#pragma unroll
      for (int nf = 0; nf < 4; ++nf)
        acc[mf][nf] = MFMAI8(Af[mf], Bf[nf], acc[mf][nf]);
  };

  // ---- prologue ----
  stage_half(0, 0, row0, 0);
  stage_half(0, 1, col0, 0);

  // ---- K-loop: 8 tiles of BK=64, fully unrolled, static buffer indices ----
#pragma unroll
  for (int t = 0; t < 7; ++t) {
    const int buf = t & 1;
    stage_half(buf ^ 1, 0, row0, (t + 1) * BK);
    stage_half(buf ^ 1, 1, col0, (t + 1) * BK);
    asm volatile("s_waitcnt vmcnt(4)" ::: "memory");  // tile t's 4 loads landed
    __builtin_amdgcn_s_barrier();
    compute(buf);
    __builtin_amdgcn_s_barrier();
  }
  asm volatile("s_waitcnt vmcnt(0)" ::: "memory");
  __builtin_amdgcn_s_barrier();
  compute(1);

  // ---- epilogue ----
  // C/D layout (16x16): col = l&15, row = (l>>4)*4 + reg
  const float SC = 2.0f * 1.44269504088896340736f / 16129.0f;  // 2*log2(e)/127^2
  const int lgrp = l >> 4;
  const int lcol = l & 15;

  float e[4][4][4];
#pragma unroll
  for (int mf = 0; mf < 4; ++mf)
#pragma unroll
    for (int nf = 0; nf < 4; ++nf)
#pragma unroll
      for (int rg = 0; rg < 4; ++rg)
        e[mf][nf][rg] = exp2f((float)acc[mf][nf][rg] * SC);

  // row sums (this wave's 64 cols)
#pragma unroll
  for (int mf = 0; mf < 4; ++mf) {
    float rs[4];
#pragma unroll
    for (int rg = 0; rg < 4; ++rg) {
      float s = 0.0f;
#pragma unroll
      for (int nf = 0; nf < 4; ++nf) s += e[mf][nf][rg];
      rs[rg] = s;
    }
#pragma unroll
    for (int off = 1; off < 16; off <<= 1) {
#pragma unroll
      for (int rg = 0; rg < 4; ++rg) rs[rg] += __shfl_xor(rs[rg], off);
    }
    if (lcol == 0) {
      const int rowb = row0 + wr + mf * 16 + lgrp * 4;
#pragma unroll
      for (int rg = 0; rg < 4; ++rg) atomicAdd(&rowsum[rowb + rg], rs[rg]);
    }
  }

  // column sums (mirror) — off-diagonal tiles only
  if (bx != by) {
#pragma unroll
    for (int nf = 0; nf < 4; ++nf) {
      float cs = 0.0f;
#pragma unroll
      for (int mf = 0; mf < 4; ++mf)
#pragma unroll
        for (int rg = 0; rg < 4; ++rg) cs += e[mf][nf][rg];
      cs += __shfl_xor(cs, 16);
      cs += __shfl_xor(cs, 32);
      if (lgrp == 0) atomicAdd(&rowsum[col0 + wc + nf * 16 + lcol], cs);
    }
  }
}

// ---------------- Kernel 3: finalize (parallel, atomic partials) ----------------
__global__ __launch_bounds__(1024) void finalize_kernel(
    const float* __restrict__ rowsum, const float* __restrict__ pd,
    float* __restrict__ out, int M, int N) {
  const int i = blockIdx.x * 1024 + threadIdx.x;
  const float E2 = 7.38905609893065f;  // exp(2) — diagonal term (unit rows)
  float acc = 0.0f;
  if (i < M) {
    const float denom = rowsum[i] - E2;
    const int kk = (i < N) ? i : (i - N);
    acc = logf(denom) - 2.0f * pd[kk];
  }
#pragma unroll
  for (int off = 32; off; off >>= 1) acc += __shfl_down(acc, off);
  __shared__ float red[16];
  const int t = threadIdx.x;
  if ((t & 63) == 0) red[t >> 6] = acc;
  __syncthreads();
  if (t < 64) {
    float s = (t < 16) ? red[t] : 0.0f;
#pragma unroll
    for (int off = 8; off; off >>= 1) s += __shfl_down(s, off);
    if (t == 0) atomicAdd(out, s / (float)M);
  }
}

extern "C" void kernel_launch(void* const* d_in, const int* in_sizes, int n_in,
                              void* d_out, int out_size, void* d_ws, size_t ws_size,
                              hipStream_t stream) {
  const float* ei = (const float*)d_in[0];
  const float* ej = (const float*)d_in[1];
  float* out = (float*)d_out;

  const int N = in_sizes[0] / DDIM;  // 4096
  const int M = 2 * N;               // 8192
  const int NT = M / 128;            // 64 tiles per dim
  const int NTRI = NT * (NT + 1) / 2;  // 2080 blocks (= 8*260)

  char* ws = (char*)d_ws;
  unsigned char* zq = (unsigned char*)ws;                        // M * 512 i8
  float* pd = (float*)(ws + (size_t)M * DDIM);                   // N f32
  float* rowsum = (float*)(ws + (size_t)M * DDIM + (size_t)N * 4);  // M f32

  norm_pd_kernel<<<N, 256, 0, stream>>>(ei, ej, zq, pd, rowsum, out, N);
  simloss_main<<<NTRI, 256, 0, stream>>>(zq, rowsum, NTRI);
  finalize_kernel<<<(M + 1023) / 1024, 1024, 0, stream>>>(rowsum, pd, out, M, N);
}